// Round 6
// baseline (137.537 us; speedup 1.0000x reference)
//
#include <hip/hip_runtime.h>
#include <hip/hip_bf16.h>

// AbsolutePositionEncoding: out[b][s][e] = E[s>>3][e]
//   b in [0,64), s in [0,2048), e in [0,256), ALL FP32 (confirmed r3:
//   absmax=0; dict order d_in[0]=x unused, d_in[1]=E 512x256).
// 134 MB pure broadcast-write -> store-BW-bound.
//
// HISTORY: r3 simple 1-store/thread: graph 131.5 us (kernel ~26 us, 5.2 TB/s).
// r4 batch-reuse (1 load, 8 stores): 133.6 NEUTRAL — loads already hidden.
// r5 nt-store attempt: COMPILE FAIL — __builtin_nontemporal_store rejects
//   HIP_vector_type<float,4>; needs a native clang ext_vector. Fixed here.
// THEORY (unchanged): residual ~5 us vs fill-rate is L2 write-allocate on a
// streamed 134 MB buffer (4x aggregate L2). nt stores -> early evict.
// If neutral: structural floor (graph = ~105 us harness fills + kernel).

typedef float floatx4 __attribute__((ext_vector_type(4)));  // native vector: nt-builtin-compatible

constexpr unsigned SEQ         = 2048;
constexpr unsigned VEC_PER_ROW = 256 / 4;                    // 64 vec4 per (b,s) row
constexpr unsigned TOTAL_VEC   = 64u * SEQ * VEC_PER_ROW;    // 8,388,608 vec4 stores

__global__ __launch_bounds__(256)
void ape_broadcast_kernel(const floatx4* __restrict__ E, floatx4* __restrict__ out) {
    unsigned v  = blockIdx.x * blockDim.x + threadIdx.x;  // < 8.4M
    unsigned e4 = v & (VEC_PER_ROW - 1);
    unsigned s  = (v >> 6) & (SEQ - 1);
    floatx4 val = E[(s >> 3) * VEC_PER_ROW + e4];   // L1/L2-hot gather (512 KB table)
    __builtin_nontemporal_store(val, &out[v]);      // global_store_dwordx4 ... nt
}

extern "C" void kernel_launch(void* const* d_in, const int* in_sizes, int n_in,
                              void* d_out, int out_size, void* d_ws, size_t ws_size,
                              hipStream_t stream) {
    const floatx4* E = (const floatx4*)d_in[1];  // dict order: [0]=x (unused), [1]=E
    floatx4* out     = (floatx4*)d_out;

    constexpr unsigned BLOCK = 256;
    constexpr unsigned GRID  = TOTAL_VEC / BLOCK;  // 32768 blocks
    ape_broadcast_kernel<<<GRID, BLOCK, 0, stream>>>(E, out);
}

// Round 7
// 131.869 us; speedup vs baseline: 1.0430x; 1.0430x over previous
//
#include <hip/hip_runtime.h>
#include <hip/hip_bf16.h>

// AbsolutePositionEncoding: out[b][s][e] = E[s>>3][e]
//   b in [0,64), s in [0,2048), e in [0,256), ALL FP32 (confirmed r3:
//   absmax=0; dict order d_in[0]=x unused, d_in[1]=E 512x256).
// 134 MB pure broadcast-write -> store-BW-bound.
//
// FINAL — experiment ledger (graph dur_us; fills = run-drift gauge):
//   r3 simple 1-store/thread : 131.5  (fills 79.9-84.8)  <- BEST, this file
//   r4 batch-reuse x8 stores : 133.6  (fills 79.9-84.8)  neutral: gather
//        loads were L1-hit and fully hidden (FETCH_SIZE ~ 0)
//   r6 nt-stores             : 137.5  (fills 85.8-87.1)  ~neutral after
//        drift: L2 write-allocate wasn't the limiter (134 MB >> 32 MB L2;
//        steady-state is HBM writeback either way)
// Structural floor: graph = ws-poison ~83 + out-poison ~21 + restores ~1
// + kernel ~21-26 us (134 MB at >=5.2 TB/s, >=81% of the device's
// demonstrated 6.4 TB/s fill rate; remainder is launch ramp/drain).

constexpr unsigned SEQ         = 2048;
constexpr unsigned VEC_PER_ROW = 256 / 4;                    // 64 float4 per (b,s) row
constexpr unsigned TOTAL_VEC   = 64u * SEQ * VEC_PER_ROW;    // 8,388,608 float4 stores

__global__ __launch_bounds__(256)
void ape_broadcast_kernel(const float4* __restrict__ E, float4* __restrict__ out) {
    unsigned v  = blockIdx.x * blockDim.x + threadIdx.x;  // < 8.4M, fits u32
    unsigned e4 = v & (VEC_PER_ROW - 1);   // 4-elem group within the row
    unsigned s  = (v >> 6) & (SEQ - 1);    // token index
    out[v] = E[(s >> 3) * VEC_PER_ROW + e4];  // L1/L2-hot gather (512 KB table)
}

extern "C" void kernel_launch(void* const* d_in, const int* in_sizes, int n_in,
                              void* d_out, int out_size, void* d_ws, size_t ws_size,
                              hipStream_t stream) {
    const float4* E = (const float4*)d_in[1];  // dict order: [0]=x (unused), [1]=E
    float4* out     = (float4*)d_out;

    constexpr unsigned BLOCK = 256;
    constexpr unsigned GRID  = TOTAL_VEC / BLOCK;  // 32768 blocks
    ape_broadcast_kernel<<<GRID, BLOCK, 0, stream>>>(E, out);
}